// Round 1
// baseline (253.784 us; speedup 1.0000x reference)
//
#include <hip/hip_runtime.h>

// KinematicWaveRouting: the reference recurrence
//   Q[j] <- max(Q[j] - CFL*(Q[j]-Q[j-1]) + u(t), 0),  CFL = 0.9, Q[0] = 0
// has all-nonnegative terms (0.1*Q[j] + 0.9*Q[j-1] + u), so max() never binds
// => linear time-invariant system. Outlet (Q[20]) is a causal FIR:
//   outlet(t) = scale_b * sum_k w[k] * runoff(t-k),  scale_b = basin_area*50
// with w[k] = P(Binom(k,0.9) <= 19): w[k]=1 for k<=19, decays ~10x/step after
// k~21 (w[31]~2e-7). K=32 taps => truncation error << threshold.
// manning_n / slope / width are unused by the reference.

#define KTAPS 32
#define RPT   8          // outputs per thread along t
#define TPB   256
#define TILE_T (TPB * RPT)  // 2048 t-values per block

struct WTab { float w[KTAPS]; };

__global__ __launch_bounds__(TPB) void kwr_fir_kernel(
    const float* __restrict__ runoff,
    const float* __restrict__ basin_area,
    float* __restrict__ out,
    int T, int tiles_per_row, WTab wt)
{
    const int blk  = blockIdx.x;
    const int b    = blk / tiles_per_row;
    const int tile = blk - b * tiles_per_row;
    const int t0   = tile * TILE_T + threadIdx.x * RPT;   // first output t

    const float* row = runoff + (size_t)b * T;

    // window: row[t0-32 .. t0+7]  (40 floats, float4-aligned: t0 % 8 == 0)
    float buf[RPT + KTAPS];
    if (t0 >= KTAPS) {
        const float4* p = (const float4*)(row + t0 - KTAPS);
        #pragma unroll
        for (int i = 0; i < (RPT + KTAPS) / 4; ++i) {
            float4 v = p[i];
            buf[4*i+0] = v.x; buf[4*i+1] = v.y;
            buf[4*i+2] = v.z; buf[4*i+3] = v.w;
        }
    } else {
        // first tile boundary: zero-pad t < 0 (only tid < 4 of tile 0)
        #pragma unroll
        for (int i = 0; i < RPT + KTAPS; ++i) {
            int idx = t0 - KTAPS + i;
            buf[i] = (idx >= 0) ? row[idx] : 0.0f;
        }
    }

    float acc[RPT];
    #pragma unroll
    for (int r = 0; r < RPT; ++r) acc[r] = 0.0f;

    // out(t0+r) = sum_k w[k] * row[t0+r-k]; buf index = 32 + r - k in [1,39]
    #pragma unroll
    for (int k = 0; k < KTAPS; ++k) {
        const float wk = wt.w[k];
        #pragma unroll
        for (int r = 0; r < RPT; ++r)
            acc[r] = fmaf(wk, buf[KTAPS + r - k], acc[r]);
    }

    const float s = basin_area[b] * 50.0f;   // (1e6 / 1000 / 3600 / 20) * DT
    float* orow = out + (size_t)b * T + t0;
    float4 o0 = make_float4(acc[0]*s, acc[1]*s, acc[2]*s, acc[3]*s);
    float4 o1 = make_float4(acc[4]*s, acc[5]*s, acc[6]*s, acc[7]*s);
    ((float4*)orow)[0] = o0;
    ((float4*)orow)[1] = o1;
}

extern "C" void kernel_launch(void* const* d_in, const int* in_sizes, int n_in,
                              void* d_out, int out_size, void* d_ws, size_t ws_size,
                              hipStream_t stream)
{
    const float* runoff     = (const float*)d_in[0];
    const float* basin_area = (const float*)d_in[1];
    float* out = (float*)d_out;

    const int B = in_sizes[1];            // basin_area has B elements
    const int T = in_sizes[0] / B;        // runoff is (B, T)

    // Impulse response of the linear recurrence, computed in double.
    // State Q[1..20] = 1 after the impulse step (w[0] = 1), then evolve
    // Q[j] = 0.1*Q[j] + 0.9*Q[j-1] homogeneously; w[k] = Q[20] after k steps.
    WTab wt;
    double Q[21];
    for (int j = 0; j <= 20; ++j) Q[j] = (j >= 1) ? 1.0 : 0.0;
    wt.w[0] = 1.0f;
    for (int k = 1; k < KTAPS; ++k) {
        for (int j = 20; j >= 1; --j) Q[j] = 0.1 * Q[j] + 0.9 * Q[j - 1];
        wt.w[k] = (float)Q[20];
    }

    const int tiles_per_row = T / TILE_T;           // 4096 / 2048 = 2
    const int nblk = B * tiles_per_row;             // 16384

    kwr_fir_kernel<<<nblk, TPB, 0, stream>>>(runoff, basin_area, out,
                                             T, tiles_per_row, wt);
}

// Round 2
// 233.867 us; speedup vs baseline: 1.0852x; 1.0852x over previous
//
#include <hip/hip_runtime.h>

// KinematicWaveRouting: the reference recurrence
//   Q[j] <- max(Q[j] - CFL*(Q[j]-Q[j-1]) + u(t), 0),  CFL = 0.9, Q[0] = 0
// is linear (all terms nonnegative => max never binds). Outlet (Q[20]) is a
// causal FIR: outlet(t) = basin_area*50 * sum_k w[k]*runoff(t-k), with
// w[k] = P(Binom(k,0.9) <= 19). w[k]=1 for k<=19, ~10x decay per step after
// k~21; K=32 taps => truncation error << threshold.
//
// R1 -> R2: previous no-LDS version had 5x global read amplification
// (40 loaded floats per 8 outputs, 16B loads at 32B lane stride) -> stuck at
// 2.2 TB/s. Now: stage tile once in LDS (unique bytes, coalesced float4),
// XOR-swizzled 16B quads (s = q ^ ((q>>3)&7)) so every ds_read_b128 hits all
// 8 bank groups uniformly (8 lanes/group == conflict-free minimum).

#define KTAPS 32
#define RPT   8                      // outputs per thread along t
#define TPB   256
#define TILE_T (TPB * RPT)           // 2048 t-values per block
#define NQ   ((TILE_T + KTAPS) / 4)  // 520 staged quads (16B) incl. 32-halo

struct WTab { float w[KTAPS]; };

__device__ __forceinline__ int swz(int q) { return q ^ ((q >> 3) & 7); }

__global__ __launch_bounds__(TPB) void kwr_fir_lds_kernel(
    const float* __restrict__ runoff,
    const float* __restrict__ basin_area,
    float* __restrict__ out,
    int T, int tiles_per_row, WTab wt)
{
    __shared__ float4 lds[NQ];

    const int tid  = threadIdx.x;
    const int blk  = blockIdx.x;
    const int b    = blk / tiles_per_row;
    const int tile = blk - b * tiles_per_row;
    const long long rowbase = (long long)b * T;
    const int tstart = tile * TILE_T - KTAPS;  // global t of LDS float j=0

    // ---- stage unique tile bytes (coalesced float4, swizzled LDS write) ----
    const float4* gsrc = (const float4*)(runoff + rowbase + tstart);
    #pragma unroll
    for (int pass = 0; pass < 3; ++pass) {     // 256*3 >= 520
        int q = tid + pass * TPB;
        if (q < NQ) {
            float4 v;
            if (tstart + 4 * q >= 0) v = gsrc[q];          // in-row (halo ok)
            else                     v = make_float4(0.f, 0.f, 0.f, 0.f);
            lds[swz(q)] = v;
        }
    }
    __syncthreads();

    // ---- window from LDS: quads 2*tid .. 2*tid+9 (floats 8*tid..8*tid+39) --
    float buf[RPT + KTAPS];
    #pragma unroll
    for (int c = 0; c < (RPT + KTAPS) / 4; ++c) {
        float4 v = lds[swz(2 * tid + c)];
        buf[4*c+0] = v.x; buf[4*c+1] = v.y;
        buf[4*c+2] = v.z; buf[4*c+3] = v.w;
    }

    float acc[RPT];
    #pragma unroll
    for (int r = 0; r < RPT; ++r) acc[r] = 0.0f;

    // out(t0+r) = sum_k w[k]*x(t0+r-k); buf holds x at floats j=8*tid+0..39,
    // output r lives at j = 8*tid + 32 + r  ->  acc[r] += w[k]*buf[32+r-k]
    #pragma unroll
    for (int k = 0; k < KTAPS; ++k) {
        const float wk = wt.w[k];
        #pragma unroll
        for (int r = 0; r < RPT; ++r)
            acc[r] = fmaf(wk, buf[KTAPS + r - k], acc[r]);
    }

    const float s = basin_area[b] * 50.0f;   // (1e6/1000/3600/20) * DT
    float* orow = out + rowbase + tile * TILE_T + tid * RPT;
    ((float4*)orow)[0] = make_float4(acc[0]*s, acc[1]*s, acc[2]*s, acc[3]*s);
    ((float4*)orow)[1] = make_float4(acc[4]*s, acc[5]*s, acc[6]*s, acc[7]*s);
}

extern "C" void kernel_launch(void* const* d_in, const int* in_sizes, int n_in,
                              void* d_out, int out_size, void* d_ws, size_t ws_size,
                              hipStream_t stream)
{
    const float* runoff     = (const float*)d_in[0];
    const float* basin_area = (const float*)d_in[1];
    float* out = (float*)d_out;

    const int B = in_sizes[1];            // basin_area has B elements
    const int T = in_sizes[0] / B;        // runoff is (B, T)

    // Impulse response of the linear recurrence, computed in double.
    WTab wt;
    double Q[21];
    for (int j = 0; j <= 20; ++j) Q[j] = (j >= 1) ? 1.0 : 0.0;
    wt.w[0] = 1.0f;
    for (int k = 1; k < KTAPS; ++k) {
        for (int j = 20; j >= 1; --j) Q[j] = 0.1 * Q[j] + 0.9 * Q[j - 1];
        wt.w[k] = (float)Q[20];
    }

    const int tiles_per_row = T / TILE_T;           // 4096 / 2048 = 2
    const int nblk = B * tiles_per_row;             // 16384

    kwr_fir_lds_kernel<<<nblk, TPB, 0, stream>>>(runoff, basin_area, out,
                                                 T, tiles_per_row, wt);
}